// Round 1
// baseline (542.667 us; speedup 1.0000x reference)
//
#include <hip/hip_runtime.h>
#include <hip/hip_bf16.h>

#define NN 200000
#define ND 128
#define GD 128
#define HID 512
#define NG 1024

typedef __bf16 bf16x8 __attribute__((ext_vector_type(8)));
typedef unsigned short u16x8 __attribute__((ext_vector_type(8)));
typedef float f32x16 __attribute__((ext_vector_type(16)));
typedef float f32x4v __attribute__((ext_vector_type(4)));

// packed-weight bases in bf16 elements inside d_ws
#define PK_WI1 0
#define PK_WI2 131072
#define PK_WJ1 196608
#define PK_WJ2 262144

__device__ __forceinline__ unsigned short f2bf(float x){
  unsigned u = __builtin_bit_cast(unsigned, x);
  u += 0x7FFFu + ((u >> 16) & 1u);          // RNE
  return (unsigned short)(u >> 16);
}
__device__ __forceinline__ float bf2f(unsigned short h){
  return __builtin_bit_cast(float, ((unsigned)h) << 16);
}
__device__ __forceinline__ f32x16 mfma_bf16(u16x8 a, u16x8 b, f32x16 c){
  return __builtin_amdgcn_mfma_f32_32x32x16_bf16(
      __builtin_bit_cast(bf16x8, a), __builtin_bit_cast(bf16x8, b), c, 0, 0, 0);
}

// ---- pack fp32 weights [K][N] -> bf16 B-fragment order for 32x32x16 ----
// frag(kt,nt): lane holds B[kt*16 + (lane>>5)*8 + j][nt*32 + (lane&31)], j=0..7
// flat elem = ((kt*(N/32) + nt)*64 + lane)*8 + j
__global__ void pack_w(const float* __restrict__ Wi1, const float* __restrict__ Wi2,
                       const float* __restrict__ Wj1, const float* __restrict__ Wj2,
                       unsigned short* __restrict__ pk){
  int g = blockIdx.x * 256 + threadIdx.x;   // 40960 groups of 8 elems
  const float* W; int N; int base; int f;
  if (g < 16384)      { W = Wi1; N = 512; base = PK_WI1; f = g; }
  else if (g < 24576) { W = Wi2; N = 128; base = PK_WI2; f = g - 16384; }
  else if (g < 32768) { W = Wj1; N = 512; base = PK_WJ1; f = g - 24576; }
  else                { W = Wj2; N = 128; base = PK_WJ2; f = g - 32768; }
  int lane = f & 63;
  int t = f >> 6;
  int ntiles = N >> 5;
  int nt = t % ntiles, kt = t / ntiles;
  int k0 = kt * 16 + (lane >> 5) * 8;
  int n  = nt * 32 + (lane & 31);
  u16x8 v;
  #pragma unroll
  for (int j = 0; j < 8; ++j) v[j] = f2bf(W[(size_t)(k0 + j) * N + n]);
  *(u16x8*)(pk + base + (size_t)f * 8) = v;
}

// ---- main fused kernel: 128 threads = 2 independent waves, 32 nodes/wave ----
__global__ __launch_bounds__(128, 2)
void readout_main(const float* __restrict__ hT, const float* __restrict__ h0,
                  const int* __restrict__ gi,
                  const float* __restrict__ bi1, const float* __restrict__ bi2,
                  const float* __restrict__ bj1, const float* __restrict__ bj2,
                  const unsigned short* __restrict__ pk,
                  float* __restrict__ out){
  __shared__ __align__(16) unsigned short Xs[64 * 264]; // bf16 [64 rows][256+8 pad]
  __shared__ __align__(16) float Ts[64 * 68];           // fp32 [64 rows][64+4 pad]
  __shared__ int gids[64];

  const int lane = threadIdx.x & 63;
  const int wv   = threadIdx.x >> 6;
  const int l31  = lane & 31;
  const int q    = lane >> 5;
  const int R0   = wv * 32;                 // this wave's local row base
  const int m0   = blockIdx.x * 64 + R0;    // global node base (200000 = 3125*64 exact)

  // ---- stage X = [h_T | h_0] as bf16 (wave-private rows, no barrier needed) ----
  #pragma unroll
  for (int it = 0; it < 16; ++it){
    int flat = it * 64 + lane;              // 0..1023
    int r  = flat >> 5;                     // 0..31
    int c4 = flat & 31;                     // float4 index within 128-col row
    const float4 vT = ((const float4*)(hT + (size_t)(m0 + r) * ND))[c4];
    const float4 v0 = ((const float4*)(h0 + (size_t)(m0 + r) * ND))[c4];
    uint2 pT, p0;
    pT.x = f2bf(vT.x) | ((unsigned)f2bf(vT.y) << 16);
    pT.y = f2bf(vT.z) | ((unsigned)f2bf(vT.w) << 16);
    p0.x = f2bf(v0.x) | ((unsigned)f2bf(v0.y) << 16);
    p0.y = f2bf(v0.z) | ((unsigned)f2bf(v0.w) << 16);
    *(uint2*)&Xs[(R0 + r) * 264 + c4 * 4]       = pT;
    *(uint2*)&Xs[(R0 + r) * 264 + 128 + c4 * 4] = p0;
  }
  if (lane < 32){
    // dtype probe: sorted indices end at 1023 -> int32 layout; int64 high word -> 0
    bool g64 = (gi[NN - 1] == 0);
    gids[R0 + lane] = g64 ? gi[2 * (m0 + lane)] : gi[m0 + lane];
  }
  asm volatile("" ::: "memory");

  const int aBase = (R0 + l31) * 264 + q * 8; // A-frag: m=lane&31, k=q*8+j
  const int tBase = (R0 + l31) * 68 + q * 8;

  f32x16 z;
  #pragma unroll
  for (int i = 0; i < 16; ++i) z[i] = 0.f;

  // ================= phase i: gate = sigmoid(MLP([h_T|h_0])) =================
  f32x16 gacc[4] = {z, z, z, z};
  for (int c = 0; c < 8; ++c){              // hidden chunk of 64 (2 n-tiles)
    f32x16 t0 = z, t1 = z;
    #pragma unroll
    for (int kt = 0; kt < 16; ++kt){        // K = 256
      u16x8 a  = *(const u16x8*)&Xs[aBase + kt * 16];
      u16x8 b0 = *(const u16x8*)(pk + PK_WI1 + (size_t)((kt * 16 + c * 2 + 0) * 64 + lane) * 8);
      u16x8 b1 = *(const u16x8*)(pk + PK_WI1 + (size_t)((kt * 16 + c * 2 + 1) * 64 + lane) * 8);
      t0 = mfma_bf16(a, b0, t0);
      t1 = mfma_bf16(a, b1, t1);
    }
    float bb0 = bi1[c * 64 + l31];
    float bb1 = bi1[c * 64 + 32 + l31];
    asm volatile("" ::: "memory");
    #pragma unroll
    for (int reg = 0; reg < 16; ++reg){     // C-layout -> Ts (A-layout source)
      int rowl = (reg & 3) + 8 * (reg >> 2) + 4 * q;
      float v0 = t0[reg] + bb0; v0 = v0 > 0.f ? v0 : 0.f;
      float v1 = t1[reg] + bb1; v1 = v1 > 0.f ? v1 : 0.f;
      Ts[(R0 + rowl) * 68 + l31]      = v0;
      Ts[(R0 + rowl) * 68 + 32 + l31] = v1;
    }
    asm volatile("" ::: "memory");
    #pragma unroll
    for (int kt2 = 0; kt2 < 4; ++kt2){      // layer2: K-chunk = 64
      f32x4v lo = *(const f32x4v*)&Ts[tBase + kt2 * 16];
      f32x4v hi = *(const f32x4v*)&Ts[tBase + kt2 * 16 + 4];
      u16x8 a2;
      a2[0]=f2bf(lo[0]); a2[1]=f2bf(lo[1]); a2[2]=f2bf(lo[2]); a2[3]=f2bf(lo[3]);
      a2[4]=f2bf(hi[0]); a2[5]=f2bf(hi[1]); a2[6]=f2bf(hi[2]); a2[7]=f2bf(hi[3]);
      #pragma unroll
      for (int nt = 0; nt < 4; ++nt){
        u16x8 b = *(const u16x8*)(pk + PK_WI2 + (size_t)(((c * 4 + kt2) * 4 + nt) * 64 + lane) * 8);
        gacc[nt] = mfma_bf16(a2, b, gacc[nt]);
      }
    }
    asm volatile("" ::: "memory");
  }
  // gate -> Xs upper half (h_0 region is dead now); bf16
  #pragma unroll
  for (int nt = 0; nt < 4; ++nt){
    int col = nt * 32 + l31;
    float bb = bi2[col];
    #pragma unroll
    for (int reg = 0; reg < 16; ++reg){
      int rowl = (reg & 3) + 8 * (reg >> 2) + 4 * q;
      float x = gacc[nt][reg] + bb;
      float s = 1.f / (1.f + __expf(-x));
      Xs[(R0 + rowl) * 264 + 128 + col] = f2bf(s);
    }
  }
  asm volatile("" ::: "memory");

  // ================= phase j: j = MLP(h_T) =================
  f32x16 jacc[4] = {z, z, z, z};
  for (int c = 0; c < 8; ++c){
    f32x16 t0 = z, t1 = z;
    #pragma unroll
    for (int kt = 0; kt < 8; ++kt){         // K = 128 (h_T only)
      u16x8 a  = *(const u16x8*)&Xs[aBase + kt * 16];
      u16x8 b0 = *(const u16x8*)(pk + PK_WJ1 + (size_t)((kt * 16 + c * 2 + 0) * 64 + lane) * 8);
      u16x8 b1 = *(const u16x8*)(pk + PK_WJ1 + (size_t)((kt * 16 + c * 2 + 1) * 64 + lane) * 8);
      t0 = mfma_bf16(a, b0, t0);
      t1 = mfma_bf16(a, b1, t1);
    }
    float bb0 = bj1[c * 64 + l31];
    float bb1 = bj1[c * 64 + 32 + l31];
    asm volatile("" ::: "memory");
    #pragma unroll
    for (int reg = 0; reg < 16; ++reg){
      int rowl = (reg & 3) + 8 * (reg >> 2) + 4 * q;
      float v0 = t0[reg] + bb0; v0 = v0 > 0.f ? v0 : 0.f;
      float v1 = t1[reg] + bb1; v1 = v1 > 0.f ? v1 : 0.f;
      Ts[(R0 + rowl) * 68 + l31]      = v0;
      Ts[(R0 + rowl) * 68 + 32 + l31] = v1;
    }
    asm volatile("" ::: "memory");
    #pragma unroll
    for (int kt2 = 0; kt2 < 4; ++kt2){
      f32x4v lo = *(const f32x4v*)&Ts[tBase + kt2 * 16];
      f32x4v hi = *(const f32x4v*)&Ts[tBase + kt2 * 16 + 4];
      u16x8 a2;
      a2[0]=f2bf(lo[0]); a2[1]=f2bf(lo[1]); a2[2]=f2bf(lo[2]); a2[3]=f2bf(lo[3]);
      a2[4]=f2bf(hi[0]); a2[5]=f2bf(hi[1]); a2[6]=f2bf(hi[2]); a2[7]=f2bf(hi[3]);
      #pragma unroll
      for (int nt = 0; nt < 4; ++nt){
        u16x8 b = *(const u16x8*)(pk + PK_WJ2 + (size_t)(((c * 4 + kt2) * 4 + nt) * 64 + lane) * 8);
        jacc[nt] = mfma_bf16(a2, b, jacc[nt]);
      }
    }
    asm volatile("" ::: "memory");
  }

  // ======== epilogue: R_v = gate * (jacc + bj2); sorted-run segmented atomics ========
  int gv[16];
  #pragma unroll
  for (int reg = 0; reg < 16; ++reg){
    int rowl = (reg & 3) + 8 * (reg >> 2) + 4 * q;
    gv[reg] = gids[R0 + rowl];
  }
  #pragma unroll
  for (int nt = 0; nt < 4; ++nt){
    int col = nt * 32 + l31;
    float bb = bj2[col];
    float acc = 0.f; int cg = -1;
    #pragma unroll
    for (int reg = 0; reg < 16; ++reg){     // reg order == ascending row order
      int rowl = (reg & 3) + 8 * (reg >> 2) + 4 * q;
      float gate = bf2f(Xs[(R0 + rowl) * 264 + 128 + col]);
      float rv = gate * (jacc[nt][reg] + bb);
      int g = gv[reg];
      if (g != cg){
        if (cg >= 0) atomicAdd(out + (size_t)cg * GD + col, acc);
        acc = 0.f; cg = g;
      }
      acc += rv;
    }
    atomicAdd(out + (size_t)cg * GD + col, acc);
  }
}

extern "C" void kernel_launch(void* const* d_in, const int* in_sizes, int n_in,
                              void* d_out, int out_size, void* d_ws, size_t ws_size,
                              hipStream_t stream){
  const float* hT  = (const float*)d_in[0];
  const float* h0  = (const float*)d_in[1];
  const int*   gi  = (const int*)d_in[2];
  const float* Wi1 = (const float*)d_in[3];
  const float* bi1 = (const float*)d_in[4];
  const float* Wi2 = (const float*)d_in[5];
  const float* bi2 = (const float*)d_in[6];
  const float* Wj1 = (const float*)d_in[7];
  const float* bj1 = (const float*)d_in[8];
  const float* Wj2 = (const float*)d_in[9];
  const float* bj2 = (const float*)d_in[10];
  float* out = (float*)d_out;
  unsigned short* pk = (unsigned short*)d_ws; // needs 655360 B

  hipMemsetAsync(out, 0, (size_t)NG * GD * sizeof(float), stream);
  pack_w<<<160, 256, 0, stream>>>(Wi1, Wi2, Wj1, Wj2, pk);
  readout_main<<<NN / 64, 128, 0, stream>>>(hT, h0, gi, bi1, bi2, bj1, bj2, pk, out);
}

// Round 2
// 466.156 us; speedup vs baseline: 1.1641x; 1.1641x over previous
//
#include <hip/hip_runtime.h>
#include <hip/hip_bf16.h>

#define NN 200000
#define ND 128
#define GD 128
#define HID 512
#define NG 1024

typedef __bf16 bf16x8 __attribute__((ext_vector_type(8)));
typedef unsigned short u16x8 __attribute__((ext_vector_type(8)));
typedef float f32x16 __attribute__((ext_vector_type(16)));

// packed-weight bases in bf16 elements inside d_ws
#define PK_WI1 0
#define PK_WI2 131072
#define PK_WJ1 196608
#define PK_WJ2 262144

__device__ __forceinline__ unsigned short f2bf(float x){
  unsigned u = __builtin_bit_cast(unsigned, x);
  u += 0x7FFFu + ((u >> 16) & 1u);          // RNE
  return (unsigned short)(u >> 16);
}
__device__ __forceinline__ float bf2f(unsigned short h){
  return __builtin_bit_cast(float, ((unsigned)h) << 16);
}
__device__ __forceinline__ f32x16 mfma_bf16(u16x8 a, u16x8 b, f32x16 c){
  return __builtin_amdgcn_mfma_f32_32x32x16_bf16(
      __builtin_bit_cast(bf16x8, a), __builtin_bit_cast(bf16x8, b), c, 0, 0, 0);
}

// ---- pack fp32 weights [K][N] -> bf16 B-fragment order for 32x32x16 ----
// frag(kt,nt): lane holds B[kt*16 + (lane>>5)*8 + j][nt*32 + (lane&31)], j=0..7
// flat elem = ((kt*(N/32) + nt)*64 + lane)*8 + j
__global__ void pack_w(const float* __restrict__ Wi1, const float* __restrict__ Wi2,
                       const float* __restrict__ Wj1, const float* __restrict__ Wj2,
                       unsigned short* __restrict__ pk){
  int g = blockIdx.x * 256 + threadIdx.x;   // 40960 groups of 8 elems
  const float* W; int N; int base; int f;
  if (g < 16384)      { W = Wi1; N = 512; base = PK_WI1; f = g; }
  else if (g < 24576) { W = Wi2; N = 128; base = PK_WI2; f = g - 16384; }
  else if (g < 32768) { W = Wj1; N = 512; base = PK_WJ1; f = g - 24576; }
  else                { W = Wj2; N = 128; base = PK_WJ2; f = g - 32768; }
  int lane = f & 63;
  int t = f >> 6;
  int ntiles = N >> 5;
  int nt = t % ntiles, kt = t / ntiles;
  int k0 = kt * 16 + (lane >> 5) * 8;
  int n  = nt * 32 + (lane & 31);
  u16x8 v;
  #pragma unroll
  for (int j = 0; j < 8; ++j) v[j] = f2bf(W[(size_t)(k0 + j) * N + n]);
  *(u16x8*)(pk + base + (size_t)f * 8) = v;
}

// ---- main fused kernel: 128 threads = 2 independent waves, 32 nodes/wave ----
__global__ __launch_bounds__(128, 2)
void readout_main(const float* __restrict__ hT, const float* __restrict__ h0,
                  const int* __restrict__ gi,
                  const float* __restrict__ bi1, const float* __restrict__ bi2,
                  const float* __restrict__ bj1, const float* __restrict__ bj2,
                  const unsigned short* __restrict__ pk,
                  float* __restrict__ out){
  __shared__ __align__(16) unsigned short Xs[64 * 264]; // bf16 [64 rows][256+8 pad]
  __shared__ __align__(16) unsigned short Ts[64 * 72];  // bf16 [64 rows][64+8 pad]
  __shared__ int gids[64];

  const int lane = threadIdx.x & 63;
  const int wv   = threadIdx.x >> 6;
  const int l31  = lane & 31;
  const int q    = lane >> 5;
  const int R0   = wv * 32;                 // this wave's local row base
  const int m0   = blockIdx.x * 64 + R0;    // global node base (200000 = 3125*64 exact)

  // ---- bias prefetch into registers (one L2 latency, overlapped with staging) ----
  float rbi1[16], rbj1[16], rbi2[4], rbj2[4];
  #pragma unroll
  for (int k = 0; k < 16; ++k){ rbi1[k] = bi1[k * 32 + l31]; rbj1[k] = bj1[k * 32 + l31]; }
  #pragma unroll
  for (int k = 0; k < 4; ++k){ rbi2[k] = bi2[k * 32 + l31]; rbj2[k] = bj2[k * 32 + l31]; }

  // ---- stage X = [h_T | h_0] as bf16 (wave-private rows, no block barrier) ----
  #pragma unroll
  for (int it = 0; it < 16; ++it){
    int flat = it * 64 + lane;              // 0..1023
    int r  = flat >> 5;                     // 0..31
    int c4 = flat & 31;                     // float4 index within 128-col row
    const float4 vT = ((const float4*)(hT + (size_t)(m0 + r) * ND))[c4];
    const float4 v0 = ((const float4*)(h0 + (size_t)(m0 + r) * ND))[c4];
    uint2 pT, p0;
    pT.x = f2bf(vT.x) | ((unsigned)f2bf(vT.y) << 16);
    pT.y = f2bf(vT.z) | ((unsigned)f2bf(vT.w) << 16);
    p0.x = f2bf(v0.x) | ((unsigned)f2bf(v0.y) << 16);
    p0.y = f2bf(v0.z) | ((unsigned)f2bf(v0.w) << 16);
    *(uint2*)&Xs[(R0 + r) * 264 + c4 * 4]       = pT;
    *(uint2*)&Xs[(R0 + r) * 264 + 128 + c4 * 4] = p0;
  }
  if (lane < 32){
    // dtype probe: sorted indices end at 1023 -> int32 layout; int64 high word -> 0
    bool g64 = (gi[NN - 1] == 0);
    gids[R0 + lane] = g64 ? gi[2 * (m0 + lane)] : gi[m0 + lane];
  }
  asm volatile("" ::: "memory");            // Xs staged before cross-lane A reads

  const int aBase = (R0 + l31) * 264 + q * 8; // A-frag: m=lane&31, k=q*8+j
  const int tBase = (R0 + l31) * 72 + q * 8;

  f32x16 z;
  #pragma unroll
  for (int i = 0; i < 16; ++i) z[i] = 0.f;

  // ================= phase i: gate = sigmoid(MLP([h_T|h_0])) =================
  f32x16 gacc[4] = {z, z, z, z};
  for (int c = 0; c < 8; ++c){              // hidden chunk of 64 (2 n-tiles)
    f32x16 t0 = z, t1 = z;
    #pragma unroll
    for (int half = 0; half < 2; ++half){   // K = 256 in two batches of 8 kt
      u16x8 bf[16];
      #pragma unroll
      for (int kt = 0; kt < 8; ++kt){       // batch-issue 16 loads, one L2 latency
        int ka = half * 8 + kt;
        bf[2 * kt]     = *(const u16x8*)(pk + PK_WI1 + (size_t)((ka * 16 + c * 2 + 0) * 64 + lane) * 8);
        bf[2 * kt + 1] = *(const u16x8*)(pk + PK_WI1 + (size_t)((ka * 16 + c * 2 + 1) * 64 + lane) * 8);
      }
      #pragma unroll
      for (int kt = 0; kt < 8; ++kt){
        int ka = half * 8 + kt;
        u16x8 a = *(const u16x8*)&Xs[aBase + ka * 16];
        t0 = mfma_bf16(a, bf[2 * kt], t0);
        t1 = mfma_bf16(a, bf[2 * kt + 1], t1);
      }
    }
    // layer-2 fragment prefetch BEFORE the transform (latency hidden under VALU)
    u16x8 b2[16];
    #pragma unroll
    for (int kt2 = 0; kt2 < 4; ++kt2)
      #pragma unroll
      for (int nt = 0; nt < 4; ++nt)
        b2[kt2 * 4 + nt] = *(const u16x8*)(pk + PK_WI2 + (size_t)(((c * 4 + kt2) * 4 + nt) * 64 + lane) * 8);
    float bb0 = rbi1[2 * c], bb1 = rbi1[2 * c + 1];
    #pragma unroll
    for (int reg = 0; reg < 16; ++reg){     // C-layout -> Ts (A-layout source), bf16
      int rowl = (reg & 3) + 8 * (reg >> 2) + 4 * q;
      float v0 = t0[reg] + bb0; v0 = v0 > 0.f ? v0 : 0.f;
      float v1 = t1[reg] + bb1; v1 = v1 > 0.f ? v1 : 0.f;
      Ts[(R0 + rowl) * 72 + l31]      = f2bf(v0);
      Ts[(R0 + rowl) * 72 + 32 + l31] = f2bf(v1);
    }
    asm volatile("" ::: "memory");          // Ts write -> cross-lane read
    #pragma unroll
    for (int kt2 = 0; kt2 < 4; ++kt2){      // layer2: K-chunk = 64
      u16x8 a2 = *(const u16x8*)&Ts[tBase + kt2 * 16];
      #pragma unroll
      for (int nt = 0; nt < 4; ++nt)
        gacc[nt] = mfma_bf16(a2, b2[kt2 * 4 + nt], gacc[nt]);
    }
  }
  // gate -> Xs upper half (h_0 region is dead now); bf16
  #pragma unroll
  for (int nt = 0; nt < 4; ++nt){
    int col = nt * 32 + l31;
    float bb = rbi2[nt];
    #pragma unroll
    for (int reg = 0; reg < 16; ++reg){
      int rowl = (reg & 3) + 8 * (reg >> 2) + 4 * q;
      float x = gacc[nt][reg] + bb;
      float s = 1.f / (1.f + __expf(-x));
      Xs[(R0 + rowl) * 264 + 128 + col] = f2bf(s);
    }
  }

  // ================= phase j: j = MLP(h_T) =================
  f32x16 jacc[4] = {z, z, z, z};
  for (int c = 0; c < 8; ++c){
    f32x16 t0 = z, t1 = z;
    u16x8 bf[16];
    #pragma unroll
    for (int kt = 0; kt < 8; ++kt){         // K = 128: single batch of 16
      bf[2 * kt]     = *(const u16x8*)(pk + PK_WJ1 + (size_t)((kt * 16 + c * 2 + 0) * 64 + lane) * 8);
      bf[2 * kt + 1] = *(const u16x8*)(pk + PK_WJ1 + (size_t)((kt * 16 + c * 2 + 1) * 64 + lane) * 8);
    }
    #pragma unroll
    for (int kt = 0; kt < 8; ++kt){
      u16x8 a = *(const u16x8*)&Xs[aBase + kt * 16];
      t0 = mfma_bf16(a, bf[2 * kt], t0);
      t1 = mfma_bf16(a, bf[2 * kt + 1], t1);
    }
    u16x8 b2[16];
    #pragma unroll
    for (int kt2 = 0; kt2 < 4; ++kt2)
      #pragma unroll
      for (int nt = 0; nt < 4; ++nt)
        b2[kt2 * 4 + nt] = *(const u16x8*)(pk + PK_WJ2 + (size_t)(((c * 4 + kt2) * 4 + nt) * 64 + lane) * 8);
    float bb0 = rbj1[2 * c], bb1 = rbj1[2 * c + 1];
    #pragma unroll
    for (int reg = 0; reg < 16; ++reg){
      int rowl = (reg & 3) + 8 * (reg >> 2) + 4 * q;
      float v0 = t0[reg] + bb0; v0 = v0 > 0.f ? v0 : 0.f;
      float v1 = t1[reg] + bb1; v1 = v1 > 0.f ? v1 : 0.f;
      Ts[(R0 + rowl) * 72 + l31]      = f2bf(v0);
      Ts[(R0 + rowl) * 72 + 32 + l31] = f2bf(v1);
    }
    asm volatile("" ::: "memory");
    #pragma unroll
    for (int kt2 = 0; kt2 < 4; ++kt2){
      u16x8 a2 = *(const u16x8*)&Ts[tBase + kt2 * 16];
      #pragma unroll
      for (int nt = 0; nt < 4; ++nt)
        jacc[nt] = mfma_bf16(a2, b2[kt2 * 4 + nt], jacc[nt]);
    }
  }
  asm volatile("" ::: "memory");            // gate writes visible for epilogue reads

  // ======== epilogue: R_v = gate * (jacc + bj2); sorted-run segmented atomics ========
  int gv[16];
  #pragma unroll
  for (int reg = 0; reg < 16; ++reg){
    int rowl = (reg & 3) + 8 * (reg >> 2) + 4 * q;
    gv[reg] = gids[R0 + rowl];
  }
  #pragma unroll
  for (int nt = 0; nt < 4; ++nt){
    int col = nt * 32 + l31;
    float bb = rbj2[nt];
    float acc = 0.f; int cg = -1;
    #pragma unroll
    for (int reg = 0; reg < 16; ++reg){     // reg order == ascending row order
      int rowl = (reg & 3) + 8 * (reg >> 2) + 4 * q;
      float gate = bf2f(Xs[(R0 + rowl) * 264 + 128 + col]);
      float rv = gate * (jacc[nt][reg] + bb);
      int g = gv[reg];
      if (g != cg){
        if (cg >= 0) atomicAdd(out + (size_t)cg * GD + col, acc);
        acc = 0.f; cg = g;
      }
      acc += rv;
    }
    atomicAdd(out + (size_t)cg * GD + col, acc);
  }
}

extern "C" void kernel_launch(void* const* d_in, const int* in_sizes, int n_in,
                              void* d_out, int out_size, void* d_ws, size_t ws_size,
                              hipStream_t stream){
  const float* hT  = (const float*)d_in[0];
  const float* h0  = (const float*)d_in[1];
  const int*   gi  = (const int*)d_in[2];
  const float* Wi1 = (const float*)d_in[3];
  const float* bi1 = (const float*)d_in[4];
  const float* Wi2 = (const float*)d_in[5];
  const float* bi2 = (const float*)d_in[6];
  const float* Wj1 = (const float*)d_in[7];
  const float* bj1 = (const float*)d_in[8];
  const float* Wj2 = (const float*)d_in[9];
  const float* bj2 = (const float*)d_in[10];
  float* out = (float*)d_out;
  unsigned short* pk = (unsigned short*)d_ws; // needs 655360 B

  hipMemsetAsync(out, 0, (size_t)NG * GD * sizeof(float), stream);
  pack_w<<<160, 256, 0, stream>>>(Wi1, Wi2, Wj1, Wj2, pk);
  readout_main<<<NN / 64, 128, 0, stream>>>(hT, h0, gi, bi1, bi2, bj1, bj2, pk, out);
}

// Round 3
// 452.933 us; speedup vs baseline: 1.1981x; 1.0292x over previous
//
#include <hip/hip_runtime.h>
#include <hip/hip_bf16.h>

#define NN 200000
#define ND 128
#define GD 128
#define HID 512
#define NG 1024

typedef __bf16 bf16x8 __attribute__((ext_vector_type(8)));
typedef unsigned short u16x8 __attribute__((ext_vector_type(8)));
typedef float f32x16 __attribute__((ext_vector_type(16)));

// packed-weight bases in bf16 elements inside d_ws
#define PK_WI1 0
#define PK_WI2 131072
#define PK_WJ1 196608
#define PK_WJ2 262144

__device__ __forceinline__ unsigned short f2bf(float x){
  unsigned u = __builtin_bit_cast(unsigned, x);
  u += 0x7FFFu + ((u >> 16) & 1u);          // RNE
  return (unsigned short)(u >> 16);
}
__device__ __forceinline__ float bf2f(unsigned short h){
  return __builtin_bit_cast(float, ((unsigned)h) << 16);
}
__device__ __forceinline__ f32x16 mfma_bf16(u16x8 a, u16x8 b, f32x16 c){
  return __builtin_amdgcn_mfma_f32_32x32x16_bf16(
      __builtin_bit_cast(bf16x8, a), __builtin_bit_cast(bf16x8, b), c, 0, 0, 0);
}

// ---- pack fp32 weights [K][N] -> bf16 B-fragment order for 32x32x16 ----
// frag(kt,nt): lane holds B[kt*16 + (lane>>5)*8 + j][nt*32 + (lane&31)], j=0..7
// flat elem = ((kt*(N/32) + nt)*64 + lane)*8 + j
// Also zeroes the output accumulator (atomics target) — replaces memset.
__global__ void pack_w(const float* __restrict__ Wi1, const float* __restrict__ Wi2,
                       const float* __restrict__ Wj1, const float* __restrict__ Wj2,
                       unsigned short* __restrict__ pk, float* __restrict__ out){
  int g = blockIdx.x * 256 + threadIdx.x;   // 40960 groups of 8 elems
  if (g < 32768) ((float4*)out)[g] = make_float4(0.f, 0.f, 0.f, 0.f); // 131072 floats
  const float* W; int N; int base; int f;
  if (g < 16384)      { W = Wi1; N = 512; base = PK_WI1; f = g; }
  else if (g < 24576) { W = Wi2; N = 128; base = PK_WI2; f = g - 16384; }
  else if (g < 32768) { W = Wj1; N = 512; base = PK_WJ1; f = g - 24576; }
  else                { W = Wj2; N = 128; base = PK_WJ2; f = g - 32768; }
  int lane = f & 63;
  int t = f >> 6;
  int ntiles = N >> 5;
  int nt = t % ntiles, kt = t / ntiles;
  int k0 = kt * 16 + (lane >> 5) * 8;
  int n  = nt * 32 + (lane & 31);
  u16x8 v;
  #pragma unroll
  for (int j = 0; j < 8; ++j) v[j] = f2bf(W[(size_t)(k0 + j) * N + n]);
  *(u16x8*)(pk + base + (size_t)f * 8) = v;
}

// ---- main fused kernel: 2 waves per block, 64 nodes per block ----
// Layer-1: hidden split across waves (wave w -> hidden cols [w*256, w*256+256)),
//          each B-fragment feeds BOTH 32-row tiles (2:1 MFMA:load).
// Layer-2: per round, block-shared Ts holds 64 hidden cols (both halves);
//          wave w accumulates its 64 output cols over the FULL hidden dim.
__global__ __launch_bounds__(128, 2)
void readout_main(const float* __restrict__ hT, const float* __restrict__ h0,
                  const int* __restrict__ gi,
                  const float* __restrict__ bi1, const float* __restrict__ bi2,
                  const float* __restrict__ bj1, const float* __restrict__ bj2,
                  const unsigned short* __restrict__ pk,
                  float* __restrict__ out){
  __shared__ __align__(16) unsigned short Xs[64 * 264];     // bf16 [64][256+8]
  __shared__ __align__(16) unsigned short Ts[2 * 64 * 72];  // bf16 dbuf [64][64+8]
  __shared__ int gids[64];

  const int lane = threadIdx.x & 63;
  const int wv   = threadIdx.x >> 6;
  const int l31  = lane & 31;
  const int q    = lane >> 5;
  const int m0   = blockIdx.x * 64;         // 200000 = 3125*64 exact

  // epilogue biases (4 regs)
  float rbi2a = bi2[wv * 64 + l31],      rbi2b = bi2[wv * 64 + 32 + l31];
  float rbj2a = bj2[wv * 64 + l31],      rbj2b = bj2[wv * 64 + 32 + l31];

  // ---- stage X = [h_T | h_0] as bf16; wave w stages rows w*32..w*32+31 ----
  #pragma unroll
  for (int it = 0; it < 16; ++it){
    int flat = it * 64 + lane;              // 0..1023
    int r  = wv * 32 + (flat >> 5);         // this wave's row
    int c4 = flat & 31;
    const float4 vT = ((const float4*)(hT + (size_t)(m0 + r) * ND))[c4];
    const float4 v0 = ((const float4*)(h0 + (size_t)(m0 + r) * ND))[c4];
    uint2 pT, p0;
    pT.x = f2bf(vT.x) | ((unsigned)f2bf(vT.y) << 16);
    pT.y = f2bf(vT.z) | ((unsigned)f2bf(vT.w) << 16);
    p0.x = f2bf(v0.x) | ((unsigned)f2bf(v0.y) << 16);
    p0.y = f2bf(v0.z) | ((unsigned)f2bf(v0.w) << 16);
    *(uint2*)&Xs[r * 264 + c4 * 4]       = pT;
    *(uint2*)&Xs[r * 264 + 128 + c4 * 4] = p0;
  }
  if (lane < 32){
    // dtype probe: sorted indices end at 1023 -> int32 layout; int64 high word -> 0
    bool g64 = (gi[NN - 1] == 0);
    int r = wv * 32 + lane;
    gids[r] = g64 ? gi[2 * (m0 + r)] : gi[m0 + r];
  }
  __syncthreads();                          // both waves read all 64 rows

  const int aB0 = l31 * 264 + q * 8;        // A-frag row-tile 0
  const int aB1 = (32 + l31) * 264 + q * 8; // A-frag row-tile 1

  f32x16 z;
  #pragma unroll
  for (int i = 0; i < 16; ++i) z[i] = 0.f;

  // ================= phase i: gate = sigmoid(MLP([h_T|h_0])) =================
  f32x16 gacc[2][2] = {{z, z}, {z, z}};     // [row-tile][col-pair], 64 VGPRs
  for (int c = 0; c < 8; ++c){
    const int ntg = wv * 8 + c;             // this wave's hidden n-tile
    float bb1 = bi1[wv * 256 + c * 32 + l31];
    u16x8 bf[16];
    #pragma unroll
    for (int kt = 0; kt < 16; ++kt)         // layer-1 B batch (K=256)
      bf[kt] = *(const u16x8*)(pk + PK_WI1 + (size_t)((kt * 16 + ntg) * 64 + lane) * 8);
    f32x16 t0 = z, t1 = z;
    #pragma unroll
    for (int kt = 0; kt < 16; ++kt){
      u16x8 a0 = *(const u16x8*)&Xs[aB0 + kt * 16];
      u16x8 a1 = *(const u16x8*)&Xs[aB1 + kt * 16];
      t0 = mfma_bf16(a0, bf[kt], t0);       // one B feeds two row-tiles
      t1 = mfma_bf16(a1, bf[kt], t1);
    }
    // layer-2 B prefetch (hidden K-chunk = 64: this round's cols, both halves)
    u16x8 b2[8];
    #pragma unroll
    for (int ks = 0; ks < 4; ++ks){
      int ktg = (ks < 2) ? (c * 2 + ks) : (16 + c * 2 + (ks - 2));
      #pragma unroll
      for (int ntl = 0; ntl < 2; ++ntl)
        b2[ks * 2 + ntl] = *(const u16x8*)(pk + PK_WI2 + (size_t)((ktg * 4 + 2 * wv + ntl) * 64 + lane) * 8);
    }
    unsigned short* Tb = Ts + (c & 1) * (64 * 72);
    #pragma unroll
    for (int reg = 0; reg < 16; ++reg){     // bias+ReLU, C-layout -> Ts
      int rowl = (reg & 3) + 8 * (reg >> 2) + 4 * q;
      float v0 = t0[reg] + bb1; v0 = v0 > 0.f ? v0 : 0.f;
      float v1 = t1[reg] + bb1; v1 = v1 > 0.f ? v1 : 0.f;
      Tb[rowl * 72 + wv * 32 + l31]        = f2bf(v0);
      Tb[(32 + rowl) * 72 + wv * 32 + l31] = f2bf(v1);
    }
    __syncthreads();                        // Ts complete (both waves)
    u16x8 a2[8];
    #pragma unroll
    for (int mt = 0; mt < 2; ++mt)
      #pragma unroll
      for (int ks = 0; ks < 4; ++ks)
        a2[mt * 4 + ks] = *(const u16x8*)&Tb[(mt * 32 + l31) * 72 + ks * 16 + q * 8];
    #pragma unroll
    for (int ks = 0; ks < 4; ++ks)
      #pragma unroll
      for (int mt = 0; mt < 2; ++mt)
        #pragma unroll
        for (int ntl = 0; ntl < 2; ++ntl)
          gacc[mt][ntl] = mfma_bf16(a2[mt * 4 + ks], b2[ks * 2 + ntl], gacc[mt][ntl]);
  }
  // gate -> Xs dead h_0 half; wave w owns cols [w*64, w*64+64)
  #pragma unroll
  for (int mt = 0; mt < 2; ++mt)
    #pragma unroll
    for (int ntl = 0; ntl < 2; ++ntl){
      int col = wv * 64 + ntl * 32 + l31;
      float bb = ntl ? rbi2b : rbi2a;
      #pragma unroll
      for (int reg = 0; reg < 16; ++reg){
        int rowl = (reg & 3) + 8 * (reg >> 2) + 4 * q;
        float x = gacc[mt][ntl][reg] + bb;
        float s = 1.f / (1.f + __expf(-x));
        Xs[(mt * 32 + rowl) * 264 + 128 + col] = f2bf(s);
      }
    }

  // ================= phase j: j = MLP(h_T) =================
  f32x16 jacc[2][2] = {{z, z}, {z, z}};
  for (int c = 0; c < 8; ++c){
    const int ntg = wv * 8 + c;
    float bb1 = bj1[wv * 256 + c * 32 + l31];
    u16x8 bf[8];
    #pragma unroll
    for (int kt = 0; kt < 8; ++kt)          // K=128 (h_T only)
      bf[kt] = *(const u16x8*)(pk + PK_WJ1 + (size_t)((kt * 16 + ntg) * 64 + lane) * 8);
    f32x16 t0 = z, t1 = z;
    #pragma unroll
    for (int kt = 0; kt < 8; ++kt){
      u16x8 a0 = *(const u16x8*)&Xs[aB0 + kt * 16];
      u16x8 a1 = *(const u16x8*)&Xs[aB1 + kt * 16];
      t0 = mfma_bf16(a0, bf[kt], t0);
      t1 = mfma_bf16(a1, bf[kt], t1);
    }
    u16x8 b2[8];
    #pragma unroll
    for (int ks = 0; ks < 4; ++ks){
      int ktg = (ks < 2) ? (c * 2 + ks) : (16 + c * 2 + (ks - 2));
      #pragma unroll
      for (int ntl = 0; ntl < 2; ++ntl)
        b2[ks * 2 + ntl] = *(const u16x8*)(pk + PK_WJ2 + (size_t)((ktg * 4 + 2 * wv + ntl) * 64 + lane) * 8);
    }
    unsigned short* Tb = Ts + (c & 1) * (64 * 72);
    #pragma unroll
    for (int reg = 0; reg < 16; ++reg){
      int rowl = (reg & 3) + 8 * (reg >> 2) + 4 * q;
      float v0 = t0[reg] + bb1; v0 = v0 > 0.f ? v0 : 0.f;
      float v1 = t1[reg] + bb1; v1 = v1 > 0.f ? v1 : 0.f;
      Tb[rowl * 72 + wv * 32 + l31]        = f2bf(v0);
      Tb[(32 + rowl) * 72 + wv * 32 + l31] = f2bf(v1);
    }
    __syncthreads();
    u16x8 a2[8];
    #pragma unroll
    for (int mt = 0; mt < 2; ++mt)
      #pragma unroll
      for (int ks = 0; ks < 4; ++ks)
        a2[mt * 4 + ks] = *(const u16x8*)&Tb[(mt * 32 + l31) * 72 + ks * 16 + q * 8];
    #pragma unroll
    for (int ks = 0; ks < 4; ++ks)
      #pragma unroll
      for (int mt = 0; mt < 2; ++mt)
        #pragma unroll
        for (int ntl = 0; ntl < 2; ++ntl)
          jacc[mt][ntl] = mfma_bf16(a2[mt * 4 + ks], b2[ks * 2 + ntl], jacc[mt][ntl]);
  }

  // ======== epilogue: R_v = gate * (jacc + bj2); sorted-run segmented atomics ========
  // wave w handles all 64 rows x its 64 cols; rows visited in ascending order.
  #pragma unroll
  for (int ntl = 0; ntl < 2; ++ntl){
    int col = wv * 64 + ntl * 32 + l31;
    float bb = ntl ? rbj2b : rbj2a;
    float acc = 0.f; int cg = -1;
    #pragma unroll
    for (int mt = 0; mt < 2; ++mt)
      #pragma unroll
      for (int reg = 0; reg < 16; ++reg){
        int rowl = (reg & 3) + 8 * (reg >> 2) + 4 * q;
        int row = mt * 32 + rowl;
        float gate = bf2f(Xs[row * 264 + 128 + col]);
        float rv = gate * (jacc[mt][ntl][reg] + bb);
        int g = gids[row];
        if (g != cg){
          if (cg >= 0) atomicAdd(out + (size_t)cg * GD + col, acc);
          acc = 0.f; cg = g;
        }
        acc += rv;
      }
    atomicAdd(out + (size_t)cg * GD + col, acc);
  }
}

extern "C" void kernel_launch(void* const* d_in, const int* in_sizes, int n_in,
                              void* d_out, int out_size, void* d_ws, size_t ws_size,
                              hipStream_t stream){
  const float* hT  = (const float*)d_in[0];
  const float* h0  = (const float*)d_in[1];
  const int*   gi  = (const int*)d_in[2];
  const float* Wi1 = (const float*)d_in[3];
  const float* bi1 = (const float*)d_in[4];
  const float* Wi2 = (const float*)d_in[5];
  const float* bi2 = (const float*)d_in[6];
  const float* Wj1 = (const float*)d_in[7];
  const float* bj1 = (const float*)d_in[8];
  const float* Wj2 = (const float*)d_in[9];
  const float* bj2 = (const float*)d_in[10];
  float* out = (float*)d_out;
  unsigned short* pk = (unsigned short*)d_ws; // needs 655360 B

  pack_w<<<160, 256, 0, stream>>>(Wi1, Wi2, Wj1, Wj2, pk, out);
  readout_main<<<NN / 64, 128, 0, stream>>>(hT, h0, gi, bi1, bi2, bj1, bj2, pk, out);
}